// Round 2
// baseline (174.261 us; speedup 1.0000x reference)
//
#include <hip/hip_runtime.h>
#include <math.h>

// ---------------- workspace layout (float offsets) ----------------
#define WS_XD     0u          // 256*4096          pooled-4 x, row-major
#define WS_S      1048576u    // 256               row sums of xd
#define WS_GPART  1048832u    // 64*128*128        Gram partials (K-split)
#define WS_G      2097408u    // 128*128           Gram region rows[0,128) cols rb-80
#define WS_COEF   2113792u    // 256*96            attn@v coefficients (xd rows 170..255)
#define WS_CONST  2138368u    // 256
#define WS_ATT    2138624u    // 256*4096          attention-1 output (B,C,64,64)
#define WS_FAC    3187200u    // 256               2 - sim
#define WS_XDS    3187456u    // 4*64*128*128      pooled-2 group-conv output
#define WS_OH     7381760u    // 256
#define WS_ALPHA  7382016u    // 256
#define WS_BETA   7382272u    // 1
#define WS_NSTAT  7382273u    // 16 (T[8], nrm[8])

__device__ __forceinline__ float bsum(float v, float* sd, int tid) {
    sd[tid] = v; __syncthreads();
    for (int off = 128; off > 0; off >>= 1) {
        if (tid < off) sd[tid] += sd[tid + off];
        __syncthreads();
    }
    float r = sd[0]; __syncthreads(); return r;
}
__device__ __forceinline__ float bmax(float v, float* sd, int tid) {
    sd[tid] = v; __syncthreads();
    for (int off = 128; off > 0; off >>= 1) {
        if (tid < off) sd[tid] = fmaxf(sd[tid], sd[tid + off]);
        __syncthreads();
    }
    float r = sd[0]; __syncthreads(); return r;
}

// ---------------- K0: noise row stats (sum, norm) ----------------
__global__ __launch_bounds__(256) void k_noise(const float* __restrict__ x,
                                               const int* __restrict__ nidx,
                                               float* __restrict__ ws) {
    __shared__ float sd[256];
    int n = blockIdx.x, tid = threadIdx.x;
    const float4* xr = (const float4*)x + (size_t)nidx[n] * 16384;
    float s = 0.f, ss = 0.f;
    for (int it = 0; it < 64; ++it) {
        float4 v = xr[it * 256 + tid];
        s  += v.x + v.y + v.z + v.w;
        ss += v.x*v.x + v.y*v.y + v.z*v.z + v.w*v.w;
    }
    float st = bsum(s, sd, tid);
    float sst = bsum(ss, sd, tid);
    if (tid == 0) { ws[WS_NSTAT + n] = st; ws[WS_NSTAT + 8 + n] = sqrtf(sst); }
}

// ---------------- K1: 4x4 maxpool + row sums ----------------
__global__ __launch_bounds__(256) void k_pool4(const float* __restrict__ x,
                                               float* __restrict__ ws) {
    __shared__ float sd[256];
    int r = blockIdx.x, tid = threadIdx.x;
    const float4* xr = (const float4*)x + (size_t)r * 16384;
    float* xd = ws + WS_XD + (size_t)r * 4096;
    float sum = 0.f;
    for (int it = 0; it < 16; ++it) {
        int o = it * 256 + tid;
        int h = o >> 6, w = o & 63;
        float m = -INFINITY;
        #pragma unroll
        for (int p = 0; p < 4; ++p) {
            float4 v = xr[(4 * h + p) * 64 + w];
            m = fmaxf(m, fmaxf(fmaxf(v.x, v.y), fmaxf(v.z, v.w)));
        }
        xd[o] = m; sum += m;
    }
    float st = bsum(sum, sd, tid);
    if (tid == 0) ws[WS_S + r] = st;
}

// ---------------- K2: Gram partials: rows[0,128) x cols[80,208), K-split 64 ----------------
__global__ __launch_bounds__(256) void k_gram(float* __restrict__ ws) {
    __shared__ __align__(16) float As[64][68];
    __shared__ __align__(16) float Bs[64][68];
    int tid = threadIdx.x, tx = tid & 15, ty = tid >> 4;
    int ra0 = blockIdx.y * 64, rb0 = 80 + blockIdx.x * 64, k0 = blockIdx.z * 64;
    const float4* xd4 = (const float4*)(ws + WS_XD);
    #pragma unroll
    for (int q = 0; q < 4; ++q) {
        int idx = q * 256 + tid;
        int row = idx >> 4, cf = idx & 15;
        float4 a = xd4[(size_t)(ra0 + row) * 1024 + (k0 >> 2) + cf];
        As[cf*4+0][row] = a.x; As[cf*4+1][row] = a.y; As[cf*4+2][row] = a.z; As[cf*4+3][row] = a.w;
        float4 b = xd4[(size_t)(rb0 + row) * 1024 + (k0 >> 2) + cf];
        Bs[cf*4+0][row] = b.x; Bs[cf*4+1][row] = b.y; Bs[cf*4+2][row] = b.z; Bs[cf*4+3][row] = b.w;
    }
    __syncthreads();
    float acc[4][4] = {};
    #pragma unroll 4
    for (int kk = 0; kk < 64; ++kk) {
        float4 a = *(const float4*)&As[kk][ty * 4];
        float4 b = *(const float4*)&Bs[kk][tx * 4];
        acc[0][0] += a.x*b.x; acc[0][1] += a.x*b.y; acc[0][2] += a.x*b.z; acc[0][3] += a.x*b.w;
        acc[1][0] += a.y*b.x; acc[1][1] += a.y*b.y; acc[1][2] += a.y*b.z; acc[1][3] += a.y*b.w;
        acc[2][0] += a.z*b.x; acc[2][1] += a.z*b.y; acc[2][2] += a.z*b.z; acc[2][3] += a.z*b.w;
        acc[3][0] += a.w*b.x; acc[3][1] += a.w*b.y; acc[3][2] += a.w*b.z; acc[3][3] += a.w*b.w;
    }
    float* gp = ws + WS_GPART + (size_t)blockIdx.z * 16384;
    #pragma unroll
    for (int i = 0; i < 4; ++i) {
        float4 o = make_float4(acc[i][0], acc[i][1], acc[i][2], acc[i][3]);
        *(float4*)&gp[(size_t)(ra0 + ty * 4 + i) * 128 + blockIdx.x * 64 + tx * 4] = o;
    }
}

// ---------------- K2b: reduce Gram partials ----------------
__global__ __launch_bounds__(256) void k_gred(float* __restrict__ ws) {
    int t = blockIdx.x * 256 + threadIdx.x;   // float4 index, 4096 total
    const float4* gp = (const float4*)(ws + WS_GPART);
    float4 s = make_float4(0.f, 0.f, 0.f, 0.f);
    for (int p = 0; p < 64; ++p) {
        float4 v = gp[(size_t)p * 4096 + t];
        s.x += v.x; s.y += v.y; s.z += v.z; s.w += v.w;
    }
    ((float4*)(ws + WS_G))[t] = s;
}

// ---------------- K3: masked softmax row -> coef/const ----------------
__global__ __launch_bounds__(256) void k_attn1(const int* __restrict__ labels,
                                               const float* __restrict__ w1,
                                               const float* __restrict__ b1,
                                               float* __restrict__ ws) {
    __shared__ float sd[256];
    __shared__ float attn_s[256];
    int i = blockIdx.x, tid = threadIdx.x;
    int labi = labels[i];
    bool validi = (labi != -1);
    int bi = (i >= 192) ? 1 : 0;
    int ji = i - bi * 192;
    int rq = bi * 64 + ji / 3;
    float wq = w1[ji], bq = b1[ji];
    int gk = 256 + tid;
    int bk = (gk >= 384) ? 2 : 1;
    int jk = gk - bk * 192;
    int rk = bk * 64 + jk / 3;
    float wk = w1[jk], bbk = b1[jk];
    int labj = labels[tid];
    bool allowed = validi && (labj == labi) && (labj != -1);
    float score = wq * wk * ws[WS_G + rq * 128 + (rk - 80)]
                + wq * bbk * ws[WS_S + rq]
                + wk * bq  * ws[WS_S + rk]
                + 4096.0f * bq * bbk;
    float sc = allowed ? score : -1e30f;
    float m = bmax(sc, sd, tid);
    float e = __expf(sc - m);
    float Z = bsum(e, sd, tid);
    float attn = validi ? (e / Z) : 0.0f;
    attn_s[tid] = attn;
    int gv = 512 + tid;
    int bv = (gv >= 576) ? 3 : 2;
    int jv = gv - bv * 192;
    float csum = bsum(attn * b1[jv], sd, tid);   // barrier also publishes attn_s
    if (tid < 96) {
        float s = 0.0f;
        if (tid < 86) {
            int rv = 170 + tid;
            int lo, hi, jadd;
            if (rv < 192) { int c = rv - 128; lo = 3 * c; if (lo < 128) lo = 128; hi = 3 * c + 2; jadd = -128; }
            else          { int c = rv - 192; lo = 3 * c; hi = 3 * c + 2; jadd = 64; }
            for (int jj = lo; jj <= hi; ++jj) s += attn_s[jj + jadd] * w1[jj];
        }
        ws[WS_COEF + i * 96 + tid] = s;
    }
    if (tid == 0) ws[WS_CONST + i] = csum;
}

// ---------------- K4: att = coef @ xd[170:256] + const ----------------
__global__ __launch_bounds__(256) void k_attmm(float* __restrict__ ws) {
    __shared__ __align__(16) float As[96][68];
    __shared__ __align__(16) float Bs[96][64];
    int tid = threadIdx.x, tx = tid & 15, ty = tid >> 4;
    int col0 = blockIdx.x * 64, row0 = blockIdx.y * 64;
    const float4* cf4 = (const float4*)(ws + WS_COEF);
    const float4* xd4 = (const float4*)(ws + WS_XD);
    #pragma unroll
    for (int q = 0; q < 6; ++q) {
        int f = q * 256 + tid;
        {
            int row = f / 24, c24 = f - row * 24;
            float4 v = cf4[(size_t)(row0 + row) * 24 + c24];
            As[c24*4+0][row] = v.x; As[c24*4+1][row] = v.y; As[c24*4+2][row] = v.z; As[c24*4+3][row] = v.w;
        }
        {
            int row = f >> 4, c16 = f & 15;
            float4 v = make_float4(0.f, 0.f, 0.f, 0.f);
            if (row < 86) v = xd4[(size_t)(170 + row) * 1024 + (col0 >> 2) + c16];
            *(float4*)&Bs[row][c16 * 4] = v;
        }
    }
    __syncthreads();
    float acc[4][4] = {};
    #pragma unroll 4
    for (int kk = 0; kk < 96; ++kk) {
        float4 a = *(const float4*)&As[kk][ty * 4];
        float4 b = *(const float4*)&Bs[kk][tx * 4];
        acc[0][0] += a.x*b.x; acc[0][1] += a.x*b.y; acc[0][2] += a.x*b.z; acc[0][3] += a.x*b.w;
        acc[1][0] += a.y*b.x; acc[1][1] += a.y*b.y; acc[1][2] += a.y*b.z; acc[1][3] += a.y*b.w;
        acc[2][0] += a.z*b.x; acc[2][1] += a.z*b.y; acc[2][2] += a.z*b.z; acc[2][3] += a.z*b.w;
        acc[3][0] += a.w*b.x; acc[3][1] += a.w*b.y; acc[3][2] += a.w*b.z; acc[3][3] += a.w*b.w;
    }
    float* att = ws + WS_ATT;
    #pragma unroll
    for (int i = 0; i < 4; ++i) {
        int row = row0 + ty * 4 + i;
        float cv = ws[WS_CONST + row];
        float4 o = make_float4(acc[i][0] + cv, acc[i][1] + cv, acc[i][2] + cv, acc[i][3] + cv);
        *(float4*)&att[(size_t)row * 4096 + col0 + tx * 4] = o;
    }
}

// ---------------- K5: sim(b,c) -> fac = 2 - sim ----------------
__global__ __launch_bounds__(256) void k_sim(const float* __restrict__ x,
                                             const int* __restrict__ nidx,
                                             const float* __restrict__ upk,
                                             const float* __restrict__ upb,
                                             float* __restrict__ ws) {
    __shared__ float sd[256];
    int r = blockIdx.x, tid = threadIdx.x;
    int b = r >> 6, c = r & 63;
    const float* att = ws + WS_ATT + (size_t)r * 4096;
    const float4* xn0 = (const float4*)x + (size_t)nidx[2 * b] * 16384;
    const float4* xn1 = (const float4*)x + (size_t)nidx[2 * b + 1] * 16384;
    const float4* k4p = (const float4*)upk + c * 4;
    float ub = upb[c];
    float4 kk0 = k4p[0], kk1 = k4p[1], kk2 = k4p[2], kk3 = k4p[3];
    float s2 = 0.f, d0 = 0.f, d1 = 0.f;
    for (int it = 0; it < 64; ++it) {
        int f = it * 256 + tid;
        int rowf = f >> 6, c4 = f & 63;
        float av = att[(rowf >> 2) * 64 + c4];
        int p = rowf & 3;
        float4 kv = (p == 0) ? kk0 : ((p == 1) ? kk1 : ((p == 2) ? kk2 : kk3));
        float4 a0 = xn0[f], a1 = xn1[f];
        float u;
        u = av * kv.x + ub; s2 += u * u; d0 += u * a0.x; d1 += u * a1.x;
        u = av * kv.y + ub; s2 += u * u; d0 += u * a0.y; d1 += u * a1.y;
        u = av * kv.z + ub; s2 += u * u; d0 += u * a0.z; d1 += u * a1.z;
        u = av * kv.w + ub; s2 += u * u; d0 += u * a0.w; d1 += u * a1.w;
    }
    s2 = bsum(s2, sd, tid);
    d0 = bsum(d0, sd, tid);
    d1 = bsum(d1, sd, tid);
    if (tid == 0) {
        float nup = fmaxf(sqrtf(s2), 1e-12f);
        float n0 = fmaxf(ws[WS_NSTAT + 8 + 2 * b], 1e-12f);
        float n1 = fmaxf(ws[WS_NSTAT + 8 + 2 * b + 1], 1e-12f);
        float sim = 0.5f * (d0 / (nup * n0) + d1 / (nup * n1));
        ws[WS_FAC + r] = 2.0f - sim;
    }
}

// ---------------- K6: fused out_clu -> group conv -> maxpool2 -> x_ds ----------------
__global__ __launch_bounds__(256) void k_cluds(const float* __restrict__ x,
                                               const float* __restrict__ upk,
                                               const float* __restrict__ upb,
                                               const float* __restrict__ cw,
                                               const float* __restrict__ cb,
                                               float* __restrict__ ws) {
    __shared__ float wcl[256];   // clu_w[g][o][i]
    __shared__ float kup[256];   // up_k for channels g*16..g*16+15
    __shared__ float cbl[16], ubl[16], fcl[16];
    int h2 = blockIdx.x, g = blockIdx.y, b = blockIdx.z;
    int t = threadIdx.x;
    wcl[t] = cw[g * 256 + t];
    kup[t] = upk[g * 256 + t];
    if (t < 16) {
        cbl[t] = cb[g * 16 + t];
        ubl[t] = upb[g * 16 + t];
        fcl[t] = ws[WS_FAC + b * 64 + g * 16 + t];
    }
    __syncthreads();
    int r0 = 2 * h2;
    int h_att = h2 >> 1, p0 = r0 & 3;
    int wa = t >> 2, q = t & 3;
    float oc0[16], oc1[16];
    const float* attb = ws + WS_ATT;
    #pragma unroll
    for (int i = 0; i < 16; ++i) {
        int cch = g * 16 + i;
        float av = attb[(size_t)(b * 64 + cch) * 4096 + h_att * 64 + wa];
        float u0 = av * kup[i * 16 + p0 * 4 + q] + ubl[i];
        float u1 = av * kup[i * 16 + (p0 + 1) * 4 + q] + ubl[i];
        const float* xrow = x + (size_t)(b * 64 + cch) * 65536;
        float x0 = xrow[r0 * 256 + t];
        float x1 = xrow[(r0 + 1) * 256 + t];
        oc0[i] = u0 + fcl[i] * x0;
        oc1[i] = u1 + fcl[i] * x1;
    }
    float* xds = ws + WS_XDS;
    #pragma unroll
    for (int o = 0; o < 16; ++o) {
        float a0 = cbl[o], a1 = cbl[o];
        #pragma unroll
        for (int i = 0; i < 16; ++i) {
            a0 += wcl[o * 16 + i] * oc0[i];
            a1 += wcl[o * 16 + i] * oc1[i];
        }
        float m = fmaxf(a0, a1);
        m = fmaxf(m, __shfl_xor(m, 1));
        if ((t & 1) == 0)
            xds[(size_t)((b * 64 + g * 16 + o) * 128 + h2) * 128 + (t >> 1)] = m;
    }
}

// ---------------- K7: head attention (online softmax over 16384) ----------------
__global__ __launch_bounds__(256) void k_attn2(const float* __restrict__ w2,
                                               float* __restrict__ ws) {
    __shared__ float ms[256], dsh[256];
    __shared__ float ns[256][16];
    int nh = blockIdx.x, b = blockIdx.y, tid = threadIdx.x;
    const float* X = ws + WS_XDS + (size_t)b * 1048576;
    float wqd[16], wkd[16], wvd[16];
    int oq[16], ok[16], ovo[16];
    #pragma unroll
    for (int d = 0; d < 16; ++d) {
        int jq = nh * 16 + d, jk = 64 + nh * 16 + d, jv = 128 + nh * 16 + d;
        wqd[d] = w2[jq]; wkd[d] = w2[jk]; wvd[d] = w2[jv];
        oq[d] = (jq / 3) * 16384; ok[d] = (jk / 3) * 16384; ovo[d] = (jv / 3) * 16384;
    }
    float m = -INFINITY, den = 0.f, num[16];
    #pragma unroll
    for (int d = 0; d < 16; ++d) num[d] = 0.f;
    for (int it = 0; it < 64; ++it) {
        int l = it * 256 + tid;
        float sc = 0.f;
        #pragma unroll
        for (int d = 0; d < 16; ++d) sc += (X[oq[d] + l] * wqd[d]) * (X[ok[d] + l] * wkd[d]);
        sc *= 0.25f;
        float vv[16];
        #pragma unroll
        for (int d = 0; d < 16; ++d) vv[d] = X[ovo[d] + l] * wvd[d];
        float nm = fmaxf(m, sc);
        float rr = __expf(m - nm), e = __expf(sc - nm);
        den = den * rr + e;
        #pragma unroll
        for (int d = 0; d < 16; ++d) num[d] = num[d] * rr + e * vv[d];
        m = nm;
    }
    ms[tid] = m; dsh[tid] = den;
    #pragma unroll
    for (int d = 0; d < 16; ++d) ns[tid][d] = num[d];
    __syncthreads();
    for (int off = 128; off > 0; off >>= 1) {
        if (tid < off) {
            float ma = ms[tid], mb = ms[tid + off];
            float M = fmaxf(ma, mb);
            float ra = __expf(ma - M), rb = __expf(mb - M);
            dsh[tid] = dsh[tid] * ra + dsh[tid + off] * rb;
            #pragma unroll
            for (int d = 0; d < 16; ++d)
                ns[tid][d] = ns[tid][d] * ra + ns[tid + off][d] * rb;
            ms[tid] = M;
        }
        __syncthreads();
    }
    if (tid < 16) ws[WS_OH + b * 64 + nh * 16 + tid] = ns[0][tid] / dsh[0];
}

// ---------------- K8: ov, ortho, sim2 -> alpha, beta ----------------
__global__ __launch_bounds__(256) void k_head(const float* __restrict__ bw,
                                              const float* __restrict__ bb,
                                              const float* __restrict__ cw,
                                              float* __restrict__ ws) {
    __shared__ float ohs[256], sd[256];
    int tid = threadIdx.x;
    ohs[tid] = ws[WS_OH + tid];
    __syncthreads();
    int b = tid >> 6, o = tid & 63;
    float s = bb[o];
    #pragma unroll 4
    for (int c2 = 0; c2 < 64; ++c2) s += bw[o * 64 + c2] * ohs[b * 64 + c2];
    float oacc = 0.f;
    for (int u = 0; u < 4; ++u) {
        int e = tid * 4 + u;
        int g = e >> 8, oo = (e >> 4) & 15, p = e & 15;
        float ss = 0.f;
        #pragma unroll
        for (int i = 0; i < 16; ++i) ss += cw[g * 256 + oo * 16 + i] * cw[g * 256 + p * 16 + i];
        float dd = ss - ((oo == p) ? 1.0f : 0.0f);
        oacc += dd * dd;
    }
    float tot = bsum(oacc, sd, tid);
    float nd = fmaxf(fabsf(s) * 256.0f, 1e-12f);
    float t0 = ws[WS_NSTAT + 2 * b], t1 = ws[WS_NSTAT + 2 * b + 1];
    float n0 = fmaxf(ws[WS_NSTAT + 8 + 2 * b], 1e-12f);
    float n1 = fmaxf(ws[WS_NSTAT + 8 + 2 * b + 1], 1e-12f);
    float sim2 = (s / nd) * 0.5f * (t0 / n0 + t1 / n1);
    ws[WS_ALPHA + tid] = (1.0f - sim2) * s;
    if (tid == 0) ws[WS_BETA] = 2.0f - tot / 1024.0f;   // 1 + ortho
}

// ---------------- K9: final out = beta*out_clu + alpha ----------------
__global__ __launch_bounds__(256) void k_final(const float* __restrict__ x,
                                               const float* __restrict__ upk,
                                               const float* __restrict__ upb,
                                               const float* __restrict__ ws,
                                               float* __restrict__ out) {
    int idx = blockIdx.x * 256 + threadIdx.x;   // float4 index
    int r = idx >> 14;
    int rem = idx & 16383;
    int rowf = rem >> 6, c4 = rem & 63;
    int c = r & 63;
    float av = ws[WS_ATT + (size_t)r * 4096 + (rowf >> 2) * 64 + c4];
    int p = rowf & 3;
    float4 kv = ((const float4*)upk)[c * 4 + p];
    float ub = upb[c];
    float fac = ws[WS_FAC + r], al = ws[WS_ALPHA + r], be = ws[WS_BETA];
    float4 xv = ((const float4*)x)[idx];
    float4 o;
    o.x = be * (av * kv.x + ub + fac * xv.x) + al;
    o.y = be * (av * kv.y + ub + fac * xv.y) + al;
    o.z = be * (av * kv.z + ub + fac * xv.z) + al;
    o.w = be * (av * kv.w + ub + fac * xv.w) + al;
    ((float4*)out)[idx] = o;
}

extern "C" void kernel_launch(void* const* d_in, const int* in_sizes, int n_in,
                              void* d_out, int out_size, void* d_ws, size_t ws_size,
                              hipStream_t stream) {
    const float* x      = (const float*)d_in[0];
    const int*   labels = (const int*)d_in[1];
    const int*   nidx   = (const int*)d_in[2];
    const float* w1     = (const float*)d_in[3];
    const float* b1     = (const float*)d_in[4];
    const float* upk    = (const float*)d_in[5];
    const float* upb    = (const float*)d_in[6];
    const float* cw     = (const float*)d_in[7];
    const float* cb     = (const float*)d_in[8];
    const float* w2     = (const float*)d_in[9];
    const float* bw     = (const float*)d_in[10];
    const float* bb     = (const float*)d_in[11];
    float* ws  = (float*)d_ws;
    float* out = (float*)d_out;

    hipLaunchKernelGGL(k_noise, dim3(8),          dim3(256), 0, stream, x, nidx, ws);
    hipLaunchKernelGGL(k_pool4, dim3(256),        dim3(256), 0, stream, x, ws);
    hipLaunchKernelGGL(k_gram,  dim3(2, 2, 64),   dim3(256), 0, stream, ws);
    hipLaunchKernelGGL(k_gred,  dim3(16),         dim3(256), 0, stream, ws);
    hipLaunchKernelGGL(k_attn1, dim3(256),        dim3(256), 0, stream, labels, w1, b1, ws);
    hipLaunchKernelGGL(k_attmm, dim3(64, 4),      dim3(256), 0, stream, ws);
    hipLaunchKernelGGL(k_sim,   dim3(256),        dim3(256), 0, stream, x, nidx, upk, upb, ws);
    hipLaunchKernelGGL(k_cluds, dim3(128, 4, 4),  dim3(256), 0, stream, x, upk, upb, cw, cb, ws);
    hipLaunchKernelGGL(k_attn2, dim3(4, 4),       dim3(256), 0, stream, w2, ws);
    hipLaunchKernelGGL(k_head,  dim3(1),          dim3(256), 0, stream, bw, bb, cw, ws);
    hipLaunchKernelGGL(k_final, dim3(16384),      dim3(256), 0, stream, x, upk, upb, ws, out);
}

// Round 3
// 119.796 us; speedup vs baseline: 1.4547x; 1.4547x over previous
//
#include <hip/hip_runtime.h>
#include <math.h>

// ---------------- workspace layout (float offsets) ----------------
#define WS_XD     0u          // 256*4096          pooled-4 x, row-major
#define WS_S      1048576u    // 256               row sums of xd
#define WS_GPART  1048832u    // 64*128*128        Gram partials (K-split)
#define WS_G      2097408u    // 128*128           Gram region rows[0,128) cols rb-80
#define WS_COEF   2113792u    // 256*96            attn@v coefficients (xd rows 170..255)
#define WS_CONST  2138368u    // 256
#define WS_ATT    2138624u    // 256*4096          attention-1 output (B,C,64,64)
#define WS_FAC    3187200u    // 256               2 - sim
#define WS_XDS    3187456u    // 4*64*128*128      pooled-2 group-conv output
#define WS_OH     7381760u    // 256
#define WS_ALPHA  7382016u    // 256
#define WS_BETA   7382272u    // 1
#define WS_NSTAT  7382273u    // 16 (T[8], nrm[8])
#define WS_P2     7382304u    // 16*32*18          attn2 softmax partials

__device__ __forceinline__ float bsum(float v, float* sd, int tid) {
    sd[tid] = v; __syncthreads();
    for (int off = 128; off > 0; off >>= 1) {
        if (tid < off) sd[tid] += sd[tid + off];
        __syncthreads();
    }
    float r = sd[0]; __syncthreads(); return r;
}
__device__ __forceinline__ float bmax(float v, float* sd, int tid) {
    sd[tid] = v; __syncthreads();
    for (int off = 128; off > 0; off >>= 1) {
        if (tid < off) sd[tid] = fmaxf(sd[tid], sd[tid + off]);
        __syncthreads();
    }
    float r = sd[0]; __syncthreads(); return r;
}

// ---------------- K0: noise row stats (sum, norm) ----------------
__global__ __launch_bounds__(256) void k_noise(const float* __restrict__ x,
                                               const int* __restrict__ nidx,
                                               float* __restrict__ ws) {
    __shared__ float sd[256];
    int n = blockIdx.x, tid = threadIdx.x;
    const float4* xr = (const float4*)x + (size_t)nidx[n] * 16384;
    float s = 0.f, ss = 0.f;
    for (int it = 0; it < 64; ++it) {
        float4 v = xr[it * 256 + tid];
        s  += v.x + v.y + v.z + v.w;
        ss += v.x*v.x + v.y*v.y + v.z*v.z + v.w*v.w;
    }
    float st = bsum(s, sd, tid);
    float sst = bsum(ss, sd, tid);
    if (tid == 0) { ws[WS_NSTAT + n] = st; ws[WS_NSTAT + 8 + n] = sqrtf(sst); }
}

// ---------------- K1: 4x4 maxpool + row sums ----------------
__global__ __launch_bounds__(256) void k_pool4(const float* __restrict__ x,
                                               float* __restrict__ ws) {
    __shared__ float sd[256];
    int r = blockIdx.x, tid = threadIdx.x;
    const float4* xr = (const float4*)x + (size_t)r * 16384;
    float* xd = ws + WS_XD + (size_t)r * 4096;
    float sum = 0.f;
    for (int it = 0; it < 16; ++it) {
        int o = it * 256 + tid;
        int h = o >> 6, w = o & 63;
        float m = -INFINITY;
        #pragma unroll
        for (int p = 0; p < 4; ++p) {
            float4 v = xr[(4 * h + p) * 64 + w];
            m = fmaxf(m, fmaxf(fmaxf(v.x, v.y), fmaxf(v.z, v.w)));
        }
        xd[o] = m; sum += m;
    }
    float st = bsum(sum, sd, tid);
    if (tid == 0) ws[WS_S + r] = st;
}

// ---------------- K2: Gram partials: rows[0,128) x cols[80,208), K-split 64 ----------------
__global__ __launch_bounds__(256) void k_gram(float* __restrict__ ws) {
    __shared__ __align__(16) float As[64][68];
    __shared__ __align__(16) float Bs[64][68];
    int tid = threadIdx.x, tx = tid & 15, ty = tid >> 4;
    int ra0 = blockIdx.y * 64, rb0 = 80 + blockIdx.x * 64, k0 = blockIdx.z * 64;
    const float4* xd4 = (const float4*)(ws + WS_XD);
    #pragma unroll
    for (int q = 0; q < 4; ++q) {
        int idx = q * 256 + tid;
        int row = idx >> 4, cf = idx & 15;
        float4 a = xd4[(size_t)(ra0 + row) * 1024 + (k0 >> 2) + cf];
        As[cf*4+0][row] = a.x; As[cf*4+1][row] = a.y; As[cf*4+2][row] = a.z; As[cf*4+3][row] = a.w;
        float4 b = xd4[(size_t)(rb0 + row) * 1024 + (k0 >> 2) + cf];
        Bs[cf*4+0][row] = b.x; Bs[cf*4+1][row] = b.y; Bs[cf*4+2][row] = b.z; Bs[cf*4+3][row] = b.w;
    }
    __syncthreads();
    float acc[4][4] = {};
    #pragma unroll 4
    for (int kk = 0; kk < 64; ++kk) {
        float4 a = *(const float4*)&As[kk][ty * 4];
        float4 b = *(const float4*)&Bs[kk][tx * 4];
        acc[0][0] += a.x*b.x; acc[0][1] += a.x*b.y; acc[0][2] += a.x*b.z; acc[0][3] += a.x*b.w;
        acc[1][0] += a.y*b.x; acc[1][1] += a.y*b.y; acc[1][2] += a.y*b.z; acc[1][3] += a.y*b.w;
        acc[2][0] += a.z*b.x; acc[2][1] += a.z*b.y; acc[2][2] += a.z*b.z; acc[2][3] += a.z*b.w;
        acc[3][0] += a.w*b.x; acc[3][1] += a.w*b.y; acc[3][2] += a.w*b.z; acc[3][3] += a.w*b.w;
    }
    float* gp = ws + WS_GPART + (size_t)blockIdx.z * 16384;
    #pragma unroll
    for (int i = 0; i < 4; ++i) {
        float4 o = make_float4(acc[i][0], acc[i][1], acc[i][2], acc[i][3]);
        *(float4*)&gp[(size_t)(ra0 + ty * 4 + i) * 128 + blockIdx.x * 64 + tx * 4] = o;
    }
}

// ---------------- K2b: reduce Gram partials ----------------
__global__ __launch_bounds__(256) void k_gred(float* __restrict__ ws) {
    int t = blockIdx.x * 256 + threadIdx.x;   // float4 index, 4096 total
    const float4* gp = (const float4*)(ws + WS_GPART);
    float4 s = make_float4(0.f, 0.f, 0.f, 0.f);
    for (int p = 0; p < 64; ++p) {
        float4 v = gp[(size_t)p * 4096 + t];
        s.x += v.x; s.y += v.y; s.z += v.z; s.w += v.w;
    }
    ((float4*)(ws + WS_G))[t] = s;
}

// ---------------- K3: masked softmax row -> coef/const ----------------
__global__ __launch_bounds__(256) void k_attn1(const int* __restrict__ labels,
                                               const float* __restrict__ w1,
                                               const float* __restrict__ b1,
                                               float* __restrict__ ws) {
    __shared__ float sd[256];
    __shared__ float attn_s[256];
    int i = blockIdx.x, tid = threadIdx.x;
    int labi = labels[i];
    bool validi = (labi != -1);
    int bi = (i >= 192) ? 1 : 0;
    int ji = i - bi * 192;
    int rq = bi * 64 + ji / 3;
    float wq = w1[ji], bq = b1[ji];
    int gk = 256 + tid;
    int bk = (gk >= 384) ? 2 : 1;
    int jk = gk - bk * 192;
    int rk = bk * 64 + jk / 3;
    float wk = w1[jk], bbk = b1[jk];
    int labj = labels[tid];
    bool allowed = validi && (labj == labi) && (labj != -1);
    float score = wq * wk * ws[WS_G + rq * 128 + (rk - 80)]
                + wq * bbk * ws[WS_S + rq]
                + wk * bq  * ws[WS_S + rk]
                + 4096.0f * bq * bbk;
    float sc = allowed ? score : -1e30f;
    float m = bmax(sc, sd, tid);
    float e = __expf(sc - m);
    float Z = bsum(e, sd, tid);
    float attn = validi ? (e / Z) : 0.0f;
    attn_s[tid] = attn;
    int gv = 512 + tid;
    int bv = (gv >= 576) ? 3 : 2;
    int jv = gv - bv * 192;
    float csum = bsum(attn * b1[jv], sd, tid);   // barrier also publishes attn_s
    if (tid < 96) {
        float s = 0.0f;
        if (tid < 86) {
            int rv = 170 + tid;
            int lo, hi, jadd;
            if (rv < 192) { int c = rv - 128; lo = 3 * c; if (lo < 128) lo = 128; hi = 3 * c + 2; jadd = -128; }
            else          { int c = rv - 192; lo = 3 * c; hi = 3 * c + 2; jadd = 64; }
            for (int jj = lo; jj <= hi; ++jj) s += attn_s[jj + jadd] * w1[jj];
        }
        ws[WS_COEF + i * 96 + tid] = s;
    }
    if (tid == 0) ws[WS_CONST + i] = csum;
}

// ---------------- K4: att = coef @ xd[170:256] + const ----------------
__global__ __launch_bounds__(256) void k_attmm(float* __restrict__ ws) {
    __shared__ __align__(16) float As[96][68];
    __shared__ __align__(16) float Bs[96][64];
    int tid = threadIdx.x, tx = tid & 15, ty = tid >> 4;
    int col0 = blockIdx.x * 64, row0 = blockIdx.y * 64;
    const float4* cf4 = (const float4*)(ws + WS_COEF);
    const float4* xd4 = (const float4*)(ws + WS_XD);
    #pragma unroll
    for (int q = 0; q < 6; ++q) {
        int f = q * 256 + tid;
        {
            int row = f / 24, c24 = f - row * 24;
            float4 v = cf4[(size_t)(row0 + row) * 24 + c24];
            As[c24*4+0][row] = v.x; As[c24*4+1][row] = v.y; As[c24*4+2][row] = v.z; As[c24*4+3][row] = v.w;
        }
        {
            int row = f >> 4, c16 = f & 15;
            float4 v = make_float4(0.f, 0.f, 0.f, 0.f);
            if (row < 86) v = xd4[(size_t)(170 + row) * 1024 + (col0 >> 2) + c16];
            *(float4*)&Bs[row][c16 * 4] = v;
        }
    }
    __syncthreads();
    float acc[4][4] = {};
    #pragma unroll 4
    for (int kk = 0; kk < 96; ++kk) {
        float4 a = *(const float4*)&As[kk][ty * 4];
        float4 b = *(const float4*)&Bs[kk][tx * 4];
        acc[0][0] += a.x*b.x; acc[0][1] += a.x*b.y; acc[0][2] += a.x*b.z; acc[0][3] += a.x*b.w;
        acc[1][0] += a.y*b.x; acc[1][1] += a.y*b.y; acc[1][2] += a.y*b.z; acc[1][3] += a.y*b.w;
        acc[2][0] += a.z*b.x; acc[2][1] += a.z*b.y; acc[2][2] += a.z*b.z; acc[2][3] += a.z*b.w;
        acc[3][0] += a.w*b.x; acc[3][1] += a.w*b.y; acc[3][2] += a.w*b.z; acc[3][3] += a.w*b.w;
    }
    float* att = ws + WS_ATT;
    #pragma unroll
    for (int i = 0; i < 4; ++i) {
        int row = row0 + ty * 4 + i;
        float cv = ws[WS_CONST + row];
        float4 o = make_float4(acc[i][0] + cv, acc[i][1] + cv, acc[i][2] + cv, acc[i][3] + cv);
        *(float4*)&att[(size_t)row * 4096 + col0 + tx * 4] = o;
    }
}

// ---------------- K5: sim(b,c) -> fac = 2 - sim ----------------
__global__ __launch_bounds__(256) void k_sim(const float* __restrict__ x,
                                             const int* __restrict__ nidx,
                                             const float* __restrict__ upk,
                                             const float* __restrict__ upb,
                                             float* __restrict__ ws) {
    __shared__ float sd[256];
    int r = blockIdx.x, tid = threadIdx.x;
    int b = r >> 6, c = r & 63;
    const float* att = ws + WS_ATT + (size_t)r * 4096;
    const float4* xn0 = (const float4*)x + (size_t)nidx[2 * b] * 16384;
    const float4* xn1 = (const float4*)x + (size_t)nidx[2 * b + 1] * 16384;
    const float4* k4p = (const float4*)upk + c * 4;
    float ub = upb[c];
    float4 kk0 = k4p[0], kk1 = k4p[1], kk2 = k4p[2], kk3 = k4p[3];
    float s2 = 0.f, d0 = 0.f, d1 = 0.f;
    for (int it = 0; it < 64; ++it) {
        int f = it * 256 + tid;
        int rowf = f >> 6, c4 = f & 63;
        float av = att[(rowf >> 2) * 64 + c4];
        int p = rowf & 3;
        float4 kv = (p == 0) ? kk0 : ((p == 1) ? kk1 : ((p == 2) ? kk2 : kk3));
        float4 a0 = xn0[f], a1 = xn1[f];
        float u;
        u = av * kv.x + ub; s2 += u * u; d0 += u * a0.x; d1 += u * a1.x;
        u = av * kv.y + ub; s2 += u * u; d0 += u * a0.y; d1 += u * a1.y;
        u = av * kv.z + ub; s2 += u * u; d0 += u * a0.z; d1 += u * a1.z;
        u = av * kv.w + ub; s2 += u * u; d0 += u * a0.w; d1 += u * a1.w;
    }
    s2 = bsum(s2, sd, tid);
    d0 = bsum(d0, sd, tid);
    d1 = bsum(d1, sd, tid);
    if (tid == 0) {
        float nup = fmaxf(sqrtf(s2), 1e-12f);
        float n0 = fmaxf(ws[WS_NSTAT + 8 + 2 * b], 1e-12f);
        float n1 = fmaxf(ws[WS_NSTAT + 8 + 2 * b + 1], 1e-12f);
        float sim = 0.5f * (d0 / (nup * n0) + d1 / (nup * n1));
        ws[WS_FAC + r] = 2.0f - sim;
    }
}

// ---------------- K6: fused out_clu -> group conv -> maxpool2 -> x_ds ----------------
__global__ __launch_bounds__(256) void k_cluds(const float* __restrict__ x,
                                               const float* __restrict__ upk,
                                               const float* __restrict__ upb,
                                               const float* __restrict__ cw,
                                               const float* __restrict__ cb,
                                               float* __restrict__ ws) {
    __shared__ float wcl[256];   // clu_w[g][o][i]
    __shared__ float kup[256];   // up_k for channels g*16..g*16+15
    __shared__ float cbl[16], ubl[16], fcl[16];
    int h2 = blockIdx.x, g = blockIdx.y, b = blockIdx.z;
    int t = threadIdx.x;
    wcl[t] = cw[g * 256 + t];
    kup[t] = upk[g * 256 + t];
    if (t < 16) {
        cbl[t] = cb[g * 16 + t];
        ubl[t] = upb[g * 16 + t];
        fcl[t] = ws[WS_FAC + b * 64 + g * 16 + t];
    }
    __syncthreads();
    int r0 = 2 * h2;
    int h_att = h2 >> 1, p0 = r0 & 3;
    int wa = t >> 2, q = t & 3;
    float oc0[16], oc1[16];
    const float* attb = ws + WS_ATT;
    #pragma unroll
    for (int i = 0; i < 16; ++i) {
        int cch = g * 16 + i;
        float av = attb[(size_t)(b * 64 + cch) * 4096 + h_att * 64 + wa];
        float u0 = av * kup[i * 16 + p0 * 4 + q] + ubl[i];
        float u1 = av * kup[i * 16 + (p0 + 1) * 4 + q] + ubl[i];
        const float* xrow = x + (size_t)(b * 64 + cch) * 65536;
        float x0 = xrow[r0 * 256 + t];
        float x1 = xrow[(r0 + 1) * 256 + t];
        oc0[i] = u0 + fcl[i] * x0;
        oc1[i] = u1 + fcl[i] * x1;
    }
    float* xds = ws + WS_XDS;
    #pragma unroll
    for (int o = 0; o < 16; ++o) {
        float a0 = cbl[o], a1 = cbl[o];
        #pragma unroll
        for (int i = 0; i < 16; ++i) {
            a0 += wcl[o * 16 + i] * oc0[i];
            a1 += wcl[o * 16 + i] * oc1[i];
        }
        float m = fmaxf(a0, a1);
        m = fmaxf(m, __shfl_xor(m, 1));
        if ((t & 1) == 0)
            xds[(size_t)((b * 64 + g * 16 + o) * 128 + h2) * 128 + (t >> 1)] = m;
    }
}

// ---------------- K7a: head attention partials (32 chunks per (b,nh)) ----------------
__global__ __launch_bounds__(256) void k_attn2a(const float* __restrict__ w2,
                                                float* __restrict__ ws) {
    __shared__ float ms[256], dsh[256];
    __shared__ float ns[256][16];
    int chunk = blockIdx.x, nh = blockIdx.y, b = blockIdx.z, tid = threadIdx.x;
    const float* X = ws + WS_XDS + (size_t)b * 1048576;
    float wqd[16], wkd[16], wvd[16];
    int oq[16], ok[16], ovo[16];
    #pragma unroll
    for (int d = 0; d < 16; ++d) {
        int jq = nh * 16 + d, jk = 64 + nh * 16 + d, jv = 128 + nh * 16 + d;
        wqd[d] = w2[jq]; wkd[d] = w2[jk]; wvd[d] = w2[jv];
        oq[d] = (jq / 3) * 16384; ok[d] = (jk / 3) * 16384; ovo[d] = (jv / 3) * 16384;
    }
    float m = -INFINITY, den = 0.f, num[16];
    #pragma unroll
    for (int d = 0; d < 16; ++d) num[d] = 0.f;
    #pragma unroll
    for (int e = 0; e < 2; ++e) {
        int l = chunk * 512 + e * 256 + tid;
        float sc = 0.f;
        #pragma unroll
        for (int d = 0; d < 16; ++d) sc += (X[oq[d] + l] * wqd[d]) * (X[ok[d] + l] * wkd[d]);
        sc *= 0.25f;
        float nm = fmaxf(m, sc);
        float rr = __expf(m - nm), ee = __expf(sc - nm);
        den = den * rr + ee;
        #pragma unroll
        for (int d = 0; d < 16; ++d) num[d] = num[d] * rr + ee * (X[ovo[d] + l] * wvd[d]);
        m = nm;
    }
    ms[tid] = m; dsh[tid] = den;
    #pragma unroll
    for (int d = 0; d < 16; ++d) ns[tid][d] = num[d];
    __syncthreads();
    for (int off = 128; off > 0; off >>= 1) {
        if (tid < off) {
            float ma = ms[tid], mb = ms[tid + off];
            float M = fmaxf(ma, mb);
            float ra = __expf(ma - M), rb = __expf(mb - M);
            dsh[tid] = dsh[tid] * ra + dsh[tid + off] * rb;
            #pragma unroll
            for (int d = 0; d < 16; ++d)
                ns[tid][d] = ns[tid][d] * ra + ns[tid + off][d] * rb;
            ms[tid] = M;
        }
        __syncthreads();
    }
    if (tid == 0) {
        float* p = ws + WS_P2 + ((size_t)(b * 4 + nh) * 32 + chunk) * 18;
        p[0] = ms[0]; p[1] = dsh[0];
        #pragma unroll
        for (int d = 0; d < 16; ++d) p[2 + d] = ns[0][d];
    }
}

// ---------------- K7b: merge 32 partials per (b,nh) ----------------
__global__ __launch_bounds__(64) void k_attn2b(float* __restrict__ ws) {
    int bh = blockIdx.x;              // b*4 + nh
    int lane = threadIdx.x;
    float m = -INFINITY, den = 0.f, num[16];
    #pragma unroll
    for (int d = 0; d < 16; ++d) num[d] = 0.f;
    if (lane < 32) {
        const float* p = ws + WS_P2 + ((size_t)bh * 32 + lane) * 18;
        m = p[0]; den = p[1];
        #pragma unroll
        for (int d = 0; d < 16; ++d) num[d] = p[2 + d];
    }
    // butterfly over the low 32 lanes (masks stay within the 32-group)
    #pragma unroll
    for (int mask = 1; mask <= 16; mask <<= 1) {
        float mo = __shfl_xor(m, mask);
        float dn = __shfl_xor(den, mask);
        float M = fmaxf(m, mo);
        float ra = __expf(m - M), rb = __expf(mo - M);
        den = den * ra + dn * rb;
        #pragma unroll
        for (int d = 0; d < 16; ++d) {
            float no = __shfl_xor(num[d], mask);
            num[d] = num[d] * ra + no * rb;
        }
        m = M;
    }
    __shared__ float outn[16];
    __shared__ float outd;
    if (lane == 0) {
        outd = den;
        #pragma unroll
        for (int d = 0; d < 16; ++d) outn[d] = num[d];
    }
    __syncthreads();
    if (lane < 16) {
        int b = bh >> 2, nh = bh & 3;
        ws[WS_OH + b * 64 + nh * 16 + lane] = outn[lane] / outd;
    }
}

// ---------------- K8: ov, ortho, sim2 -> alpha, beta ----------------
__global__ __launch_bounds__(256) void k_head(const float* __restrict__ bw,
                                              const float* __restrict__ bb,
                                              const float* __restrict__ cw,
                                              float* __restrict__ ws) {
    __shared__ float ohs[256], sd[256];
    int tid = threadIdx.x;
    ohs[tid] = ws[WS_OH + tid];
    __syncthreads();
    int b = tid >> 6, o = tid & 63;
    float s = bb[o];
    #pragma unroll 4
    for (int c2 = 0; c2 < 64; ++c2) s += bw[o * 64 + c2] * ohs[b * 64 + c2];
    float oacc = 0.f;
    for (int u = 0; u < 4; ++u) {
        int e = tid * 4 + u;
        int g = e >> 8, oo = (e >> 4) & 15, p = e & 15;
        float ss = 0.f;
        #pragma unroll
        for (int i = 0; i < 16; ++i) ss += cw[g * 256 + oo * 16 + i] * cw[g * 256 + p * 16 + i];
        float dd = ss - ((oo == p) ? 1.0f : 0.0f);
        oacc += dd * dd;
    }
    float tot = bsum(oacc, sd, tid);
    float nd = fmaxf(fabsf(s) * 256.0f, 1e-12f);
    float t0 = ws[WS_NSTAT + 2 * b], t1 = ws[WS_NSTAT + 2 * b + 1];
    float n0 = fmaxf(ws[WS_NSTAT + 8 + 2 * b], 1e-12f);
    float n1 = fmaxf(ws[WS_NSTAT + 8 + 2 * b + 1], 1e-12f);
    float sim2 = (s / nd) * 0.5f * (t0 / n0 + t1 / n1);
    ws[WS_ALPHA + tid] = (1.0f - sim2) * s;
    if (tid == 0) ws[WS_BETA] = 2.0f - tot / 1024.0f;   // 1 + ortho
}

// ---------------- K9: final out = beta*out_clu + alpha ----------------
__global__ __launch_bounds__(256) void k_final(const float* __restrict__ x,
                                               const float* __restrict__ upk,
                                               const float* __restrict__ upb,
                                               const float* __restrict__ ws,
                                               float* __restrict__ out) {
    int idx = blockIdx.x * 256 + threadIdx.x;   // float4 index
    int r = idx >> 14;
    int rem = idx & 16383;
    int rowf = rem >> 6, c4 = rem & 63;
    int c = r & 63;
    float av = ws[WS_ATT + (size_t)r * 4096 + (rowf >> 2) * 64 + c4];
    int p = rowf & 3;
    float4 kv = ((const float4*)upk)[c * 4 + p];
    float ub = upb[c];
    float fac = ws[WS_FAC + r], al = ws[WS_ALPHA + r], be = ws[WS_BETA];
    float4 xv = ((const float4*)x)[idx];
    float4 o;
    o.x = be * (av * kv.x + ub + fac * xv.x) + al;
    o.y = be * (av * kv.y + ub + fac * xv.y) + al;
    o.z = be * (av * kv.z + ub + fac * xv.z) + al;
    o.w = be * (av * kv.w + ub + fac * xv.w) + al;
    ((float4*)out)[idx] = o;
}

extern "C" void kernel_launch(void* const* d_in, const int* in_sizes, int n_in,
                              void* d_out, int out_size, void* d_ws, size_t ws_size,
                              hipStream_t stream) {
    const float* x      = (const float*)d_in[0];
    const int*   labels = (const int*)d_in[1];
    const int*   nidx   = (const int*)d_in[2];
    const float* w1     = (const float*)d_in[3];
    const float* b1     = (const float*)d_in[4];
    const float* upk    = (const float*)d_in[5];
    const float* upb    = (const float*)d_in[6];
    const float* cw     = (const float*)d_in[7];
    const float* cb     = (const float*)d_in[8];
    const float* w2     = (const float*)d_in[9];
    const float* bw     = (const float*)d_in[10];
    const float* bb     = (const float*)d_in[11];
    float* ws  = (float*)d_ws;
    float* out = (float*)d_out;

    hipLaunchKernelGGL(k_noise,  dim3(8),          dim3(256), 0, stream, x, nidx, ws);
    hipLaunchKernelGGL(k_pool4,  dim3(256),        dim3(256), 0, stream, x, ws);
    hipLaunchKernelGGL(k_gram,   dim3(2, 2, 64),   dim3(256), 0, stream, ws);
    hipLaunchKernelGGL(k_gred,   dim3(16),         dim3(256), 0, stream, ws);
    hipLaunchKernelGGL(k_attn1,  dim3(256),        dim3(256), 0, stream, labels, w1, b1, ws);
    hipLaunchKernelGGL(k_attmm,  dim3(64, 4),      dim3(256), 0, stream, ws);
    hipLaunchKernelGGL(k_sim,    dim3(256),        dim3(256), 0, stream, x, nidx, upk, upb, ws);
    hipLaunchKernelGGL(k_cluds,  dim3(128, 4, 4),  dim3(256), 0, stream, x, upk, upb, cw, cb, ws);
    hipLaunchKernelGGL(k_attn2a, dim3(32, 4, 4),   dim3(256), 0, stream, w2, ws);
    hipLaunchKernelGGL(k_attn2b, dim3(16),         dim3(64),  0, stream, ws);
    hipLaunchKernelGGL(k_head,   dim3(1),          dim3(256), 0, stream, bw, bb, cw, ws);
    hipLaunchKernelGGL(k_final,  dim3(16384),      dim3(256), 0, stream, x, upk, upb, ws, out);
}